// Round 4
// baseline (198.865 us; speedup 1.0000x reference)
//
#include <hip/hip_runtime.h>
#include <hip/hip_cooperative_groups.h>
#include <math.h>

namespace cg = cooperative_groups;

// Problem constants (fixed by the reference's setup_inputs)
constexpr int B = 16, A = 3, S = 80, C = 80, N = 32;
constexpr int CELLS = B * A * S * S;     // 307200
constexpr int CH = 5 + C;                // 85
constexpr int PLANE = S * S;             // 6400 floats per channel plane
constexpr float EPS = 1e-7f;

constexpr int N_DENSE_BLK = 300;         // 300 blocks * 256 thr * 4 floats = 307200 conf vals
constexpr int NT = B * N;                // 512 targets, one wave each
constexpr int N_OBJ_BLK = NT / 4;        // 128
constexpr int GRID = N_DENSE_BLK + N_OBJ_BLK;   // 428 blocks, all co-resident (<= 4/CU easily)
constexpr size_t OBJ_OFF = 4096;         // bytes; double densePart[300] at ws+0

__device__ __forceinline__ float softplusf(float x) {
    return fmaxf(x, 0.0f) + log1pf(expf(-fabsf(x)));
}

// ---- single cooperative kernel: partials -> grid.sync() -> block 0 finalize ----
__global__ void __launch_bounds__(256) yolo_all(const float* __restrict__ preds,
                                                const float* __restrict__ anchors,
                                                const int* __restrict__ tcls,
                                                const float* __restrict__ tbox,
                                                double* __restrict__ densePart,
                                                float* __restrict__ objPart,
                                                float* __restrict__ out) {
    int wave = threadIdx.x >> 6, lane = threadIdx.x & 63;

    if (blockIdx.x < N_DENSE_BLK) {
        // ===== dense: sum softplus(conf) over all 48 conf planes, branch-free =====
        int g = blockIdx.x * 256 + threadIdx.x;      // [0, 76800)
        int p = g / 1600;                            // plane id 0..47
        int r = g - p * 1600;                        // float4 within plane
        int b = p / 3, a = p - b * 3;
        const float4* src = (const float4*)preds;
        float4 v = src[(size_t)(b * (A * CH) + a * CH + 4) * (PLANE / 4) + r];
        float s = softplusf(v.x) + softplusf(v.y) + softplusf(v.z) + softplusf(v.w);
        #pragma unroll
        for (int off = 32; off > 0; off >>= 1) s += __shfl_down(s, off);
        __shared__ float sm[4];
        if (lane == 0) sm[wave] = s;
        __syncthreads();
        if (threadIdx.x == 0)
            densePart[blockIdx.x] = (double)(sm[0] + sm[1] + sm[2] + sm[3]);
    } else {
        // ===== sparse: one wave per target =====
        int t = (blockIdx.x - N_DENSE_BLK) * 4 + wave;   // [0, 512)
        int b = t >> 5, n = t & 31;

        float aw[A], ah[A];
        #pragma unroll
        for (int a = 0; a < A; a++) { aw[a] = anchors[a * 2]; ah[a] = anchors[a * 2 + 1]; }

        // lanes 0..31: cell key for target (b, lane); identical math to reference
        int key = -1;
        if (lane < N) {
            float4 tb = ((const float4*)tbox)[b * N + lane];
            int gi = min(max((int)floorf(tb.x * (float)S), 0), S - 1);
            int gj = min(max((int)floorf(tb.y * (float)S), 0), S - 1);
            float tw = tb.z * 640.0f, th = tb.w * 640.0f;
            int ba = 0; float best = -1.0f;
            #pragma unroll
            for (int a = 0; a < A; a++) {                // strict > : first-max == jnp.argmax
                float inter = fminf(tw, aw[a]) * fminf(th, ah[a]);
                float uni = tw * th + aw[a] * ah[a] - inter;
                float r = inter / uni;
                if (r > best) { best = r; ba = a; }
            }
            key = (ba * S + gj) * S + gi;
        }
        int my_key = __shfl(key, n);
        unsigned long long eq = __ballot(key == my_key);
        // last-write-wins: winner iff no target n2 in (n, N) maps to the same cell
        bool winner = (eq & 0xFFFFFFFFull & ~((2ull << n) - 1ull)) == 0;

        float r_ciou = 0.f, r_obj = 0.f, r_corr = 0.f, r_cls = 0.f, r_cnt = 0.f;
        if (winner) {                                    // wave-uniform branch
            int ba = my_key / (S * S);
            int rem = my_key - ba * (S * S);
            int gj = rem / S, gi = rem - gj * S;
            int base = (b * (A * CH) + ba * CH) * PLANE + gj * S + gi;

            // class loss, lane-parallel: lane covers c=lane and c=lane+64
            int cls = tcls[b * N + n];
            float l0 = preds[base + (5 + lane) * PLANE];
            float scls = softplusf(l0) - ((lane == cls) ? l0 : 0.f);
            if (lane < C - 64) {
                float l1 = preds[base + (5 + 64 + lane) * PLANE];
                scls += softplusf(l1) - (((64 + lane) == cls) ? l1 : 0.f);
            }
            #pragma unroll
            for (int off = 32; off > 0; off >>= 1) scls += __shfl_down(scls, off);
            r_cls = scls;                                // valid in lane 0

            // box + conf (broadcast loads, computed redundantly on all lanes)
            float conf = preds[base + 4 * PLANE];
            float sp = softplusf(conf);
            r_obj = sp - conf;                           // bce(conf, 1)
            r_corr = sp;                                 // remove from noobj sum
            r_cnt = 1.f;
            float tx = preds[base + 0 * PLANE], ty = preds[base + 1 * PLANE];
            float twl = preds[base + 2 * PLANE], thl = preds[base + 3 * PLANE];
            float pcx = (1.0f / (1.0f + expf(-tx)) + (float)gi) * 8.0f;
            float pcy = (1.0f / (1.0f + expf(-ty)) + (float)gj) * 8.0f;
            float pw = aw[ba] * expf(twl), ph = ah[ba] * expf(thl);
            float px1 = pcx - pw * 0.5f, px2 = pcx + pw * 0.5f;
            float py1 = pcy - ph * 0.5f, py2 = pcy + ph * 0.5f;
            int ti = (b * N + n) * 4;
            float cx = tbox[ti + 0] * 640.0f, cy = tbox[ti + 1] * 640.0f;
            float tw = tbox[ti + 2] * 640.0f, th = tbox[ti + 3] * 640.0f;
            float tx1 = cx - tw * 0.5f, tx2 = cx + tw * 0.5f;
            float ty1 = cy - th * 0.5f, ty2 = cy + th * 0.5f;
            float iw = fmaxf(fminf(px2, tx2) - fmaxf(px1, tx1), 0.0f);
            float ih = fmaxf(fminf(py2, ty2) - fmaxf(py1, ty1), 0.0f);
            float inter = iw * ih;
            float pa = fmaxf(px2 - px1, 0.0f) * fmaxf(py2 - py1, 0.0f);
            float ta = fmaxf(tx2 - tx1, 0.0f) * fmaxf(ty2 - ty1, 0.0f);
            float uni = pa + ta - inter + EPS;
            float iou = inter / uni;
            float dx = (px1 + px2) * 0.5f - (tx1 + tx2) * 0.5f;
            float dy = (py1 + py2) * 0.5f - (ty1 + ty2) * 0.5f;
            float cdist = dx * dx + dy * dy;
            float ew = fmaxf(px2, tx2) - fminf(px1, tx1);
            float eh = fmaxf(py2, ty2) - fminf(py1, ty1);
            float ediag = ew * ew + eh * eh + EPS;
            float pwc = fmaxf(px2 - px1, EPS), phc = fmaxf(py2 - py1, EPS);
            float twc = fmaxf(tx2 - tx1, EPS), thc = fmaxf(ty2 - ty1, EPS);
            float dv = atanf(twc / thc) - atanf(pwc / phc);
            float v = (float)(4.0 / (M_PI * M_PI)) * dv * dv;
            float alpha = v / (1.0f - iou + v + EPS);
            r_ciou = iou - cdist / ediag - alpha * v;
        }
        if (lane == 0) {                                 // every wave writes its slot: no memset needed
            float* dst = objPart + (size_t)t * 8;
            ((float4*)dst)[0] = make_float4(r_ciou, r_obj, r_corr, r_cls);
            ((float4*)dst)[1] = make_float4(r_cnt, 0.f, 0.f, 0.f);
        }
    }

    // ===== grid-wide barrier, then block 0 finalizes =====
    cg::this_grid().sync();
    if (blockIdx.x != 0) return;

    double sp = 0, ciou = 0, obj = 0, corr = 0, cls = 0, cnt = 0;
    for (int i = threadIdx.x; i < N_DENSE_BLK; i += 256) sp += densePart[i];
    for (int t = threadIdx.x; t < NT; t += 256) {
        const float* p = objPart + (size_t)t * 8;
        ciou += p[0]; obj += p[1]; corr += p[2]; cls += p[3]; cnt += p[4];
    }
    #pragma unroll
    for (int off = 32; off > 0; off >>= 1) {
        sp   += __shfl_down(sp, off);   ciou += __shfl_down(ciou, off);
        obj  += __shfl_down(obj, off);  corr += __shfl_down(corr, off);
        cls  += __shfl_down(cls, off);  cnt  += __shfl_down(cnt, off);
    }
    __shared__ double smf[6][4];
    if (lane == 0) {
        smf[0][wave] = sp;  smf[1][wave] = ciou; smf[2][wave] = obj;
        smf[3][wave] = corr; smf[4][wave] = cls; smf[5][wave] = cnt;
    }
    __syncthreads();
    if (threadIdx.x == 0) {
        double T[6];
        for (int k = 0; k < 6; k++) T[k] = smf[k][0] + smf[k][1] + smf[k][2] + smf[k][3];
        double nobj = T[5];
        double noobj_sum = T[0] - T[3];              // total softplus - obj cells' softplus
        double d_obj = fmax(nobj, 1.0);
        double d_no  = fmax((double)CELLS - nobj, 1.0);
        double d_cls = fmax(nobj * (double)C, 1.0);
        double loss = (1.0 - T[1] / d_obj) + T[2] / d_obj
                    + 0.5 * (noobj_sum / d_no) + T[4] / d_cls;
        out[0] = (float)loss;
    }
}

extern "C" void kernel_launch(void* const* d_in, const int* in_sizes, int n_in,
                              void* d_out, int out_size, void* d_ws, size_t ws_size,
                              hipStream_t stream) {
    const float* preds   = (const float*)d_in[0];
    const float* anchors = (const float*)d_in[1];
    const int*   tcls    = (const int*)d_in[2];
    const float* tbox    = (const float*)d_in[3];

    double* densePart = (double*)d_ws;                      // [300]
    float*  objPart   = (float*)((char*)d_ws + OBJ_OFF);    // [512*8]
    float*  out       = (float*)d_out;

    void* args[] = { (void*)&preds, (void*)&anchors, (void*)&tcls, (void*)&tbox,
                     (void*)&densePart, (void*)&objPart, (void*)&out };
    hipLaunchCooperativeKernel((const void*)yolo_all, dim3(GRID), dim3(256),
                               args, 0, stream);
}

// Round 5
// 137.258 us; speedup vs baseline: 1.4488x; 1.4488x over previous
//
#include <hip/hip_runtime.h>
#include <math.h>

// Problem constants (fixed by the reference's setup_inputs)
constexpr int B = 16, A = 3, S = 80, C = 80, N = 32;
constexpr int CELLS = B * A * S * S;     // 307200
constexpr int CH = 5 + C;                // 85
constexpr int PLANE = S * S;             // 6400 floats per channel plane
constexpr float EPS = 1e-7f;

constexpr int N_DENSE_BLK = 300;         // 300 blocks * 256 thr * 4 floats = 307200 conf vals
constexpr int NT = B * N;                // 512 targets, one wave each
constexpr int N_OBJ_BLK = NT / 4;        // 128
constexpr size_t OBJ_OFF = 4096;         // bytes; double densePart[300] at ws+0

__device__ __forceinline__ float softplusf(float x) {
    return fmaxf(x, 0.0f) + log1pf(expf(-fabsf(x)));
}

// ---- fused: blocks [0,300) dense conf sum; blocks [300,428) sparse obj ----
__global__ void __launch_bounds__(256) yolo_fused(const float* __restrict__ preds,
                                                  const float* __restrict__ anchors,
                                                  const int* __restrict__ tcls,
                                                  const float* __restrict__ tbox,
                                                  double* __restrict__ densePart,
                                                  float* __restrict__ objPart) {
    int wave = threadIdx.x >> 6, lane = threadIdx.x & 63;

    if (blockIdx.x < N_DENSE_BLK) {
        // ===== dense: sum softplus(conf) over all 48 conf planes, branch-free =====
        int g = blockIdx.x * 256 + threadIdx.x;      // [0, 76800)
        int p = g / 1600;                            // plane id 0..47
        int r = g - p * 1600;                        // float4 within plane
        int b = p / 3, a = p - b * 3;
        const float4* src = (const float4*)preds;
        float4 v = src[(size_t)(b * (A * CH) + a * CH + 4) * (PLANE / 4) + r];
        float s = softplusf(v.x) + softplusf(v.y) + softplusf(v.z) + softplusf(v.w);
        #pragma unroll
        for (int off = 32; off > 0; off >>= 1) s += __shfl_down(s, off);
        __shared__ float sm[4];
        if (lane == 0) sm[wave] = s;
        __syncthreads();
        if (threadIdx.x == 0)
            densePart[blockIdx.x] = (double)(sm[0] + sm[1] + sm[2] + sm[3]);
        return;
    }

    // ===== sparse: one wave per target =====
    int t = (blockIdx.x - N_DENSE_BLK) * 4 + wave;   // [0, 512)
    int b = t >> 5, n = t & 31;

    float aw[A], ah[A];
    #pragma unroll
    for (int a = 0; a < A; a++) { aw[a] = anchors[a * 2]; ah[a] = anchors[a * 2 + 1]; }

    // lanes 0..31: cell key for target (b, lane); identical math to reference
    int key = -1;
    if (lane < N) {
        float4 tb = ((const float4*)tbox)[b * N + lane];
        int gi = min(max((int)floorf(tb.x * (float)S), 0), S - 1);
        int gj = min(max((int)floorf(tb.y * (float)S), 0), S - 1);
        float tw = tb.z * 640.0f, th = tb.w * 640.0f;
        int ba = 0; float best = -1.0f;
        #pragma unroll
        for (int a = 0; a < A; a++) {                // strict > : first-max == jnp.argmax
            float inter = fminf(tw, aw[a]) * fminf(th, ah[a]);
            float uni = tw * th + aw[a] * ah[a] - inter;
            float r = inter / uni;
            if (r > best) { best = r; ba = a; }
        }
        key = (ba * S + gj) * S + gi;
    }
    int my_key = __shfl(key, n);
    unsigned long long eq = __ballot(key == my_key);
    // last-write-wins: winner iff no target n2 in (n, N) maps to the same cell
    bool winner = (eq & 0xFFFFFFFFull & ~((2ull << n) - 1ull)) == 0;

    float r_ciou = 0.f, r_obj = 0.f, r_corr = 0.f, r_cls = 0.f, r_cnt = 0.f;
    if (winner) {                                    // wave-uniform branch
        int ba = my_key / (S * S);
        int rem = my_key - ba * (S * S);
        int gj = rem / S, gi = rem - gj * S;
        int base = (b * (A * CH) + ba * CH) * PLANE + gj * S + gi;

        // class loss, lane-parallel: lane covers c=lane and c=lane+64
        int cls = tcls[b * N + n];
        float l0 = preds[base + (5 + lane) * PLANE];
        float scls = softplusf(l0) - ((lane == cls) ? l0 : 0.f);
        if (lane < C - 64) {
            float l1 = preds[base + (5 + 64 + lane) * PLANE];
            scls += softplusf(l1) - (((64 + lane) == cls) ? l1 : 0.f);
        }
        #pragma unroll
        for (int off = 32; off > 0; off >>= 1) scls += __shfl_down(scls, off);
        r_cls = scls;                                // valid in lane 0

        // box + conf (broadcast loads, computed redundantly on all lanes)
        float conf = preds[base + 4 * PLANE];
        float sp = softplusf(conf);
        r_obj = sp - conf;                           // bce(conf, 1)
        r_corr = sp;                                 // remove from noobj sum
        r_cnt = 1.f;
        float tx = preds[base + 0 * PLANE], ty = preds[base + 1 * PLANE];
        float twl = preds[base + 2 * PLANE], thl = preds[base + 3 * PLANE];
        float pcx = (1.0f / (1.0f + expf(-tx)) + (float)gi) * 8.0f;
        float pcy = (1.0f / (1.0f + expf(-ty)) + (float)gj) * 8.0f;
        float pw = aw[ba] * expf(twl), ph = ah[ba] * expf(thl);
        float px1 = pcx - pw * 0.5f, px2 = pcx + pw * 0.5f;
        float py1 = pcy - ph * 0.5f, py2 = pcy + ph * 0.5f;
        int ti = (b * N + n) * 4;
        float cx = tbox[ti + 0] * 640.0f, cy = tbox[ti + 1] * 640.0f;
        float tw = tbox[ti + 2] * 640.0f, th = tbox[ti + 3] * 640.0f;
        float tx1 = cx - tw * 0.5f, tx2 = cx + tw * 0.5f;
        float ty1 = cy - th * 0.5f, ty2 = cy + th * 0.5f;
        float iw = fmaxf(fminf(px2, tx2) - fmaxf(px1, tx1), 0.0f);
        float ih = fmaxf(fminf(py2, ty2) - fmaxf(py1, ty1), 0.0f);
        float inter = iw * ih;
        float pa = fmaxf(px2 - px1, 0.0f) * fmaxf(py2 - py1, 0.0f);
        float ta = fmaxf(tx2 - tx1, 0.0f) * fmaxf(ty2 - ty1, 0.0f);
        float uni = pa + ta - inter + EPS;
        float iou = inter / uni;
        float dx = (px1 + px2) * 0.5f - (tx1 + tx2) * 0.5f;
        float dy = (py1 + py2) * 0.5f - (ty1 + ty2) * 0.5f;
        float cdist = dx * dx + dy * dy;
        float ew = fmaxf(px2, tx2) - fminf(px1, tx1);
        float eh = fmaxf(py2, ty2) - fminf(py1, ty1);
        float ediag = ew * ew + eh * eh + EPS;
        float pwc = fmaxf(px2 - px1, EPS), phc = fmaxf(py2 - py1, EPS);
        float twc = fmaxf(tx2 - tx1, EPS), thc = fmaxf(ty2 - ty1, EPS);
        float dv = atanf(twc / thc) - atanf(pwc / phc);
        float v = (float)(4.0 / (M_PI * M_PI)) * dv * dv;
        float alpha = v / (1.0f - iou + v + EPS);
        r_ciou = iou - cdist / ediag - alpha * v;
    }
    if (lane == 0) {                                 // every wave writes its slot: no memset needed
        float* dst = objPart + (size_t)t * 8;
        ((float4*)dst)[0] = make_float4(r_ciou, r_obj, r_corr, r_cls);
        ((float4*)dst)[1] = make_float4(r_cnt, 0.f, 0.f, 0.f);
    }
}

// ---- finalize: sum 300 dense partials + 512 obj partials, emit scalar loss ----
__global__ void __launch_bounds__(256) yolo_fin(const double* __restrict__ densePart,
                                                const float* __restrict__ objPart,
                                                float* __restrict__ out) {
    double sp = 0, ciou = 0, obj = 0, corr = 0, cls = 0, cnt = 0;
    for (int i = threadIdx.x; i < N_DENSE_BLK; i += 256) sp += densePart[i];
    for (int t = threadIdx.x; t < NT; t += 256) {
        float4 p0 = ((const float4*)(objPart + (size_t)t * 8))[0];
        float4 p1 = ((const float4*)(objPart + (size_t)t * 8))[1];
        ciou += p0.x; obj += p0.y; corr += p0.z; cls += p0.w; cnt += p1.x;
    }
    #pragma unroll
    for (int off = 32; off > 0; off >>= 1) {
        sp   += __shfl_down(sp, off);   ciou += __shfl_down(ciou, off);
        obj  += __shfl_down(obj, off);  corr += __shfl_down(corr, off);
        cls  += __shfl_down(cls, off);  cnt  += __shfl_down(cnt, off);
    }
    __shared__ double sm[6][4];
    int wave = threadIdx.x >> 6, lane = threadIdx.x & 63;
    if (lane == 0) {
        sm[0][wave] = sp;  sm[1][wave] = ciou; sm[2][wave] = obj;
        sm[3][wave] = corr; sm[4][wave] = cls; sm[5][wave] = cnt;
    }
    __syncthreads();
    if (threadIdx.x == 0) {
        double T[6];
        for (int k = 0; k < 6; k++) T[k] = sm[k][0] + sm[k][1] + sm[k][2] + sm[k][3];
        double nobj = T[5];
        double noobj_sum = T[0] - T[3];              // total softplus - obj cells' softplus
        double d_obj = fmax(nobj, 1.0);
        double d_no  = fmax((double)CELLS - nobj, 1.0);
        double d_cls = fmax(nobj * (double)C, 1.0);
        double loss = (1.0 - T[1] / d_obj) + T[2] / d_obj
                    + 0.5 * (noobj_sum / d_no) + T[4] / d_cls;
        out[0] = (float)loss;
    }
}

extern "C" void kernel_launch(void* const* d_in, const int* in_sizes, int n_in,
                              void* d_out, int out_size, void* d_ws, size_t ws_size,
                              hipStream_t stream) {
    const float* preds   = (const float*)d_in[0];
    const float* anchors = (const float*)d_in[1];
    const int*   tcls    = (const int*)d_in[2];
    const float* tbox    = (const float*)d_in[3];

    double* densePart = (double*)d_ws;                      // [300]
    float*  objPart   = (float*)((char*)d_ws + OBJ_OFF);    // [512*8]

    yolo_fused<<<N_DENSE_BLK + N_OBJ_BLK, 256, 0, stream>>>(
        preds, anchors, tcls, tbox, densePart, objPart);
    yolo_fin<<<1, 256, 0, stream>>>(densePart, objPart, (float*)d_out);
}